// Round 6
// baseline (196.766 us; speedup 1.0000x reference)
//
#include <hip/hip_runtime.h>
#include <hip/hip_bf16.h>
#include <hip/hip_fp16.h>

// B=2048, D=256, K=256, NC=64, F=512.
// Q[b,c] = Qlin[b,c] + z^T M_c z, M_c = sum_k cq[c,k] Gamma_k.
// R13 = R12 + qf 3-buffer ring (48KB LDS, still 3 blk/CU) with counted
// vmcnt(4) + raw s_barrier: each stage gets 2 compute phases to land
// instead of 1 (the per-step vmcnt(0) drain of __syncthreads removed).
// mc: gamma loads nontemporal (64MB read-once stream; stop L2 eviction).
// FP order identical to R12 (same absmax).

#define B_SZ 2048
#define D_SZ 256
#define K_SZ 256
#define NC_SZ 64
#define F_SZ 512
#define P_SZ 65536

typedef float  floatx4  __attribute__((ext_vector_type(4)));
typedef float  floatx16 __attribute__((ext_vector_type(16)));
typedef _Float16 h8 __attribute__((ext_vector_type(8)));
typedef __fp16  fp16x2 __attribute__((ext_vector_type(2)));
union H8U4 { uint4 u; h8 h; };

// ws layout (f32 offsets).
#define WS_BEFF  49152    // 64
#define WS_CSQ   49216    // 64
#define WS_MH    196736   // f16[64*65536] M-image (written mc, read qf)
#define WS_WALL  2293888  // 7 x 32KB pre-swizzled f16 images = 224 KB
#define WS_PART  2351232  // 35 x 131072 f32 partials (qf ig 0..31, lin2 s 0..2)
#define WS_DOT   6938752  // 131072 f32: z·cq  (slab 35)
// end: 7069824 f32 = 28.3 MB

__device__ __forceinline__ unsigned pkrtz_u(float a, float b) {
    fp16x2 r = __builtin_amdgcn_cvt_pkrtz(a, b);
    return __builtin_bit_cast(unsigned, r);
}
__device__ __forceinline__ _Float16 h16rtz(float x) {
    fp16x2 r = __builtin_amdgcn_cvt_pkrtz(x, x);
    return (_Float16)r[0];
}
__device__ __forceinline__ unsigned packh2(_Float16 a, _Float16 b) {
    union { _Float16 h[2]; unsigned u; } r; r.h[0] = a; r.h[1] = b; return r.u;
}

__device__ __forceinline__ void gload16(const void* g, void* l) {
    __builtin_amdgcn_global_load_lds(
        (const __attribute__((address_space(1))) unsigned*)g,
        (__attribute__((address_space(3))) unsigned*)l, 16, 0, 0);
}

// ---------------- mid: mc(bid<1024) U prep(bid>=1024) ----------------------
__global__ __launch_bounds__(256, 4) void mid_kernel(
        const float* __restrict__ gamma, const float* __restrict__ cq,
        const float* __restrict__ Wqz,  const float* __restrict__ bqz,
        const float* __restrict__ Wqf,  const float* __restrict__ bqf,
        float* __restrict__ ws, _Float16* __restrict__ mh) {
    __shared__ float cqL[64*129];   // 33 KB (prep path only)
    const int tid = threadIdx.x;
    const int bid = blockIdx.x;

    if (bid < 1024) {   // ---- mc ----
        const int w = tid >> 6, lane = tid & 63;
        const int ln = lane & 31, half = lane >> 5;
        const int mt = w >> 1, ns = w & 1;
        const int p0 = bid * 64;
        const int iseg = p0 >> 8, j0 = p0 & 255;
        const int rot = bid & 15;

        floatx16 acc;
        #pragma unroll
        for (int r = 0; r < 16; ++r) acc[r] = 0.f;

        const int arow = mt*32 + ln;
        const float* __restrict__ cqrow = cq + arow*256;
        const float* __restrict__ gbase =
            gamma + (size_t)(half*8)*P_SZ + p0 + ns*32 + ln;

        #pragma unroll 2
        for (int t = 0; t < 16; ++t) {
            const int kc = (t + rot) & 15;
            float g[8];
            #pragma unroll
            for (int kk = 0; kk < 8; ++kk)
                g[kk] = __builtin_nontemporal_load(
                    gbase + (size_t)(kc*16 + kk)*P_SZ);   // read-once stream
            const floatx4* cp = (const floatx4*)(cqrow + kc*16 + half*8);
            floatx4 ca = cp[0], cb = cp[1];
            H8U4 a;
            a.u.x = pkrtz_u(ca[0], ca[1]); a.u.y = pkrtz_u(ca[2], ca[3]);
            a.u.z = pkrtz_u(cb[0], cb[1]); a.u.w = pkrtz_u(cb[2], cb[3]);
            H8U4 b;
            b.u.x = pkrtz_u(g[0], g[1]);
            b.u.y = pkrtz_u(g[2], g[3]);
            b.u.z = pkrtz_u(g[4], g[5]);
            b.u.w = pkrtz_u(g[6], g[7]);
            acc = __builtin_amdgcn_mfma_f32_32x32x16_f16(a.h, b.h, acc, 0, 0, 0);
        }
        // D: col=lane&31 (p), row=(r&3)+8*(r>>2)+4*half (c)  [m74/m101]
        #pragma unroll
        for (int r = 0; r < 16; ++r) {
            const int cc = mt*32 + (r&3) + 8*(r>>2) + 4*half;
            const int j  = j0 + ns*32 + ln;
            const int jc = j >> 3, off = j & 7;
            mh[(size_t)cc*P_SZ + iseg*256 + ((jc ^ (cc&31))*8 + off)] =
                (_Float16)acc[r];
        }
        return;
    }

    // ---- prep ----
    const int pbid = bid - 1024;      // 0..192
    const int w = tid >> 6, c = tid & 63;
    char* wall = (char*)(ws + WS_WALL);

    float a0 = 0.f, a1 = 0.f, a2 = 0.f, a3 = 0.f;
    float bacc = 0.f, cacc = 0.f, cqv = 0.f;
    const int i_or_j = (pbid < 64) ? pbid*4 + w :
                       (pbid < 192) ? (pbid - 64)*4 + w : 0;

    for (int h = 0; h < 2; ++h) {
        #pragma unroll
        for (int s8 = 0; s8 < 8; ++s8) {
            const int e4 = s8*256 + tid;
            const int row = e4 >> 5, col4 = (e4 & 31)*4;
            floatx4 v = *(const floatx4*)(cq + row*256 + h*128 + col4);
            #pragma unroll
            for (int u = 0; u < 4; ++u) cqL[row*129 + col4 + u] = v[u];
        }
        __syncthreads();

        if (pbid < 64) {
            const int i = i_or_j;
            #pragma unroll 8
            for (int kk = 0; kk < 128; kk += 4) {
                const int k = h*128 + kk;
                a0 = fmaf(cqL[c*129 + kk    ], Wqz[(k    )*D_SZ + i], a0);
                a1 = fmaf(cqL[c*129 + kk + 1], Wqz[(k + 1)*D_SZ + i], a1);
                a2 = fmaf(cqL[c*129 + kk + 2], Wqz[(k + 2)*D_SZ + i], a2);
                a3 = fmaf(cqL[c*129 + kk + 3], Wqz[(k + 3)*D_SZ + i], a3);
            }
            if ((i >> 7) == h) cqv = cqL[c*129 + (i & 127)];
        } else if (pbid < 192) {
            const int j = i_or_j;
            #pragma unroll 8
            for (int kk = 0; kk < 128; kk += 4) {
                const int k = h*128 + kk;
                a0 = fmaf(cqL[c*129 + kk    ], Wqf[(k    )*F_SZ + j], a0);
                a1 = fmaf(cqL[c*129 + kk + 1], Wqf[(k + 1)*F_SZ + j], a1);
                a2 = fmaf(cqL[c*129 + kk + 2], Wqf[(k + 2)*F_SZ + j], a2);
                a3 = fmaf(cqL[c*129 + kk + 3], Wqf[(k + 3)*F_SZ + j], a3);
            }
        } else {
            if (w == 0) {
                for (int kk = 0; kk < 128; ++kk) {
                    const int k = h*128 + kk;
                    bacc = fmaf(cqL[c*129 + kk], bqz[k] + bqf[k], bacc);
                }
            } else if (w == 1) {
                for (int ii = 0; ii < 128; ++ii) {
                    const float v = cqL[c*129 + ii];
                    cacc = fmaf(v, v, cacc);
                }
            }
        }
        __syncthreads();
    }

    if (pbid < 64) {
        const int i = i_or_j;
        const int boff = c*512 + ((((i >> 3) & 31) ^ (c & 31)) << 4) + (i & 7)*2;
        *(_Float16*)(wall + 0*32768 + boff) = (_Float16)((a0 + a1) + (a2 + a3));
        const _Float16 vh = (_Float16)cqv;
        *(_Float16*)(wall + 5*32768 + boff) = vh;
        *(_Float16*)(wall + 6*32768 + boff) = h16rtz((cqv - (float)vh) * 1024.f);
    } else if (pbid < 192) {
        const int j = i_or_j;
        const float acc = (a0 + a1) + (a2 + a3);
        const int row = j & 255;
        const int sbase = (j < 256) ? 1 : 3;
        const int boff = c*512 + ((((row >> 3) & 31) ^ (c & 31)) << 4) + (row & 7)*2;
        const _Float16 ah = (_Float16)acc;
        *(_Float16*)(wall + (size_t)sbase*32768 + boff) = ah;
        *(_Float16*)(wall + (size_t)(sbase + 1)*32768 + boff) =
            h16rtz((acc - (float)ah) * 1024.f);
    } else {
        if (w == 0) ws[WS_BEFF + c] = bacc;
        else if (w == 1) ws[WS_CSQ + c] = cacc;
    }
}

// ---------------- qflin: lin2(bid<64) U qf(bid>=64) -------------------------
// qf: 3-buffer 16KB ring (48KB LDS total -> still 3 blk/CU), stages issued
// 2 ahead, counted vmcnt(4) + raw s_barrier (never vmcnt(0) mid-loop).
// Ordering per step: wait(own stage) -> barrier(all waves) -> issue
// stage(t+2) (overwrites buffer whose ds_reads were consumed pre-barrier)
// -> compute buf[t%3].
__global__ __launch_bounds__(256, 3) void qflin_kernel(
        const float* __restrict__ z, const float* __restrict__ feat,
        const _Float16* __restrict__ mh, const float* __restrict__ wall_f,
        float* __restrict__ part, float* __restrict__ dot) {
    __shared__ __align__(16) char bt[3][16384];
    const int tid = threadIdx.x;
    const int w = tid >> 6, lane = tid & 63;
    const int ln = lane & 31, half = lane >> 5;

    if (blockIdx.x >= 64) {   // ---- qf ----
        const int bid = blockIdx.x - 64;
        const int xcd = bid & 7;
        const int y   = bid >> 3;          // 0..63
        const int ig  = xcd*4 + (y & 3);   // 0..31
        const int b0  = (y >> 2) * 128;
        const int bb  = b0 + w*32 + ln;

        #define STAGE_Q(ii, hs, sel)                                          \
            _Pragma("unroll")                                                 \
            for (int e0 = 0; e0 < 4; ++e0) {                                  \
                const int e = e0*256 + tid;                                   \
                const int cc = e >> 4, up = e & 15;                           \
                const int u = (((hs) ^ ((cc >> 4) & 1)) << 4) | up;           \
                gload16((const char*)mh +                                     \
                        ((size_t)cc*P_SZ + (size_t)(ii)*256)*2 + u*16,        \
                        bt[sel] + e*16);                                      \
            }

        STAGE_Q(ig*8, 0, 0);   // t=0 slab; DMA overlaps the z prologue
        STAGE_Q(ig*8, 1, 1);   // t=1 slab

        uint4 zjh[16];
        #pragma unroll
        for (int ch = 0; ch < 16; ++ch) {
            const floatx4* zp = (const floatx4*)(z + bb*D_SZ + ch*16 + half*8);
            floatx4 a = zp[0], b = zp[1];
            zjh[ch].x = pkrtz_u(a[0], a[1]);
            zjh[ch].y = pkrtz_u(a[2], a[3]);
            zjh[ch].z = pkrtz_u(b[0], b[1]);
            zjh[ch].w = pkrtz_u(b[2], b[3]);
        }
        float ziv[8];
        {
            const floatx4* zp = (const floatx4*)(z + bb*D_SZ + ig*8);
            floatx4 a = zp[0], b = zp[1];
            #pragma unroll
            for (int t = 0; t < 4; ++t) { ziv[t] = a[t]; ziv[4+t] = b[t]; }
        }

        floatx16 acc0, acc1;
        #pragma unroll
        for (int r = 0; r < 16; ++r) { acc0[r] = 0.f; acc1[r] = 0.f; }

        // Per step T: wait own stage(T) [vmcnt: stage(T),stage(T+1) out ->
        // 4 ok; last step 0], barrier, issue stage(T+2), compute buf[T%3].
        #define QF_STEP(T, VMN)                                               \
        {                                                                     \
            asm volatile("s_waitcnt vmcnt(" #VMN ")" ::: "memory");           \
            __builtin_amdgcn_s_barrier();                                     \
            if ((T) < 14) {                                                   \
                STAGE_Q(ig*8 + (((T)+2) >> 1), ((T)+2) & 1, ((T)+2) % 3);     \
            }                                                                 \
            const int il = (T) >> 1, hs = (T) & 1;                            \
            const float zi = ziv[il];                                         \
            const unsigned zu = pkrtz_u(zi, zi);                              \
            H8U4 zb; zb.u.x = zu; zb.u.y = zu; zb.u.z = zu; zb.u.w = zu;      \
            const char* btc = bt[(T) % 3];                                    \
            __builtin_amdgcn_s_setprio(1);                                    \
            _Pragma("unroll")                                                 \
            for (int chp = 0; chp < 8; ++chp) {                               \
                H8U4 aj; aj.u = zjh[hs*8 + chp];                              \
                h8 af = aj.h * zb.h;                                          \
                const int po = (((chp*2 + half) ^ (ln & 15)) << 4);           \
                H8U4 f0, f1;                                                  \
                f0.u = *(const uint4*)(btc + ln*256 + po);                    \
                f1.u = *(const uint4*)(btc + 8192 + ln*256 + po);             \
                acc0 = __builtin_amdgcn_mfma_f32_32x32x16_f16(af, f0.h, acc0, 0, 0, 0); \
                acc1 = __builtin_amdgcn_mfma_f32_32x32x16_f16(af, f1.h, acc1, 0, 0, 0); \
            }                                                                 \
            __builtin_amdgcn_s_setprio(0);                                    \
        }

        QF_STEP(0, 4);  QF_STEP(1, 4);  QF_STEP(2, 4);  QF_STEP(3, 4);
        QF_STEP(4, 4);  QF_STEP(5, 4);  QF_STEP(6, 4);  QF_STEP(7, 4);
        QF_STEP(8, 4);  QF_STEP(9, 4);  QF_STEP(10, 4); QF_STEP(11, 4);
        QF_STEP(12, 4); QF_STEP(13, 4); QF_STEP(14, 4); QF_STEP(15, 0);
        #undef QF_STEP
        #undef STAGE_Q

        float* __restrict__ qp = part + (size_t)ig * (B_SZ * NC_SZ);
        #pragma unroll
        for (int r = 0; r < 16; ++r) {
            const int row  = (r&3) + 8*(r>>2) + 4*half;
            const int brow = b0 + w*32 + row;
            qp[brow*NC_SZ + ln]      = acc0[r];
            qp[brow*NC_SZ + 32 + ln] = acc1[r];
        }
        return;
    }

    // ---- lin2 ----
    const char* wall = (const char*)wall_f;
    const int lbid = blockIdx.x;
    const int b0 = (lbid >> 2) * 128;
    const int s  = lbid & 3;
    const int bb = b0 + w*32 + ln;
    const int s_hi = (s == 0) ? 0 : (s == 1) ? 1 : (s == 2) ? 3 : 5;
    const float* __restrict__ arow =
        (s == 0 || s == 3) ? z + bb*D_SZ : feat + bb*F_SZ + (s == 2 ? 256 : 0);

    #define STAGE_L(img, h, sel)                                              \
        _Pragma("unroll")                                                     \
        for (int e0 = 0; e0 < 4; ++e0) {                                      \
            const int e = e0*256 + tid;                                       \
            const int cc = e >> 4, up = e & 15;                               \
            const int u = (((h) ^ ((cc >> 4) & 1)) << 4) | up;                \
            gload16(wall + (size_t)(img)*32768 + cc*512 + u*16,               \
                    bt[sel] + e*16);                                          \
        }

    floatx16 hh0, hh1, lh0, lh1, hl0, hl1;
    #pragma unroll
    for (int r = 0; r < 16; ++r) {
        hh0[r] = 0.f; hh1[r] = 0.f; lh0[r] = 0.f;
        lh1[r] = 0.f; hl0[r] = 0.f; hl1[r] = 0.f;
    }

    for (int h = 0; h < 2; ++h) {
        STAGE_L(s_hi, h, 0);
        if (s > 0) { STAGE_L(s_hi + 1, h, 1); }
        __syncthreads();

        #pragma unroll
        for (int chp = 0; chp < 8; ++chp) {
            const int kb = h*128 + chp*16 + half*8;
            const floatx4* ap = (const floatx4*)(arow + kb);
            floatx4 a4 = ap[0], b4 = ap[1];
            float vv[8];
            #pragma unroll
            for (int t = 0; t < 4; ++t) { vv[t] = a4[t]; vv[4+t] = b4[t]; }
            _Float16 hc[8];
            #pragma unroll
            for (int j = 0; j < 8; ++j) hc[j] = (_Float16)vv[j];
            H8U4 ah;
            ah.u.x = packh2(hc[0], hc[1]); ah.u.y = packh2(hc[2], hc[3]);
            ah.u.z = packh2(hc[4], hc[5]); ah.u.w = packh2(hc[6], hc[7]);

            const int po = (((chp*2 + half) ^ (ln & 15)) << 4);
            H8U4 f0, f1;
            f0.u = *(const uint4*)(bt[0] + ln*256 + po);
            f1.u = *(const uint4*)(bt[0] + 8192 + ln*256 + po);
            hh0 = __builtin_amdgcn_mfma_f32_32x32x16_f16(ah.h, f0.h, hh0, 0, 0, 0);
            hh1 = __builtin_amdgcn_mfma_f32_32x32x16_f16(ah.h, f1.h, hh1, 0, 0, 0);

            if (s > 0) {
                float l[8];
                #pragma unroll
                for (int j = 0; j < 8; ++j) l[j] = (vv[j] - (float)hc[j]) * 1024.f;
                H8U4 al;
                al.u.x = pkrtz_u(l[0], l[1]); al.u.y = pkrtz_u(l[2], l[3]);
                al.u.z = pkrtz_u(l[4], l[5]); al.u.w = pkrtz_u(l[6], l[7]);
                H8U4 g0, g1;
                g0.u = *(const uint4*)(bt[1] + ln*256 + po);
                g1.u = *(const uint4*)(bt[1] + 8192 + ln*256 + po);
                lh0 = __builtin_amdgcn_mfma_f32_32x32x16_f16(al.h, f0.h, lh0, 0, 0, 0);
                lh1 = __builtin_amdgcn_mfma_f32_32x32x16_f16(al.h, f1.h, lh1, 0, 0, 0);
                hl0 = __builtin_amdgcn_mfma_f32_32x32x16_f16(ah.h, g0.h, hl0, 0, 0, 0);
                hl1 = __builtin_amdgcn_mfma_f32_32x32x16_f16(ah.h, g1.h, hl1, 0, 0, 0);
            }
        }
        if (h == 0) __syncthreads();   // protect bt before restage
    }
    #undef STAGE_L

    const float is = 1.0f / 1024.0f;
    float* __restrict__ qp = part + (size_t)(32 + s) * (B_SZ * NC_SZ);
    #pragma unroll
    for (int r = 0; r < 16; ++r) {
        const int row  = (r&3) + 8*(r>>2) + 4*half;
        const int brow = b0 + w*32 + row;
        float v0 = hh0[r], v1 = hh1[r];
        if (s > 0) { v0 += (lh0[r] + hl0[r])*is; v1 += (lh1[r] + hl1[r])*is; }
        if (s < 3) {
            qp[brow*NC_SZ + ln]      = v0;
            qp[brow*NC_SZ + 32 + ln] = v1;
        } else {
            dot[brow*NC_SZ + ln]      = v0;
            dot[brow*NC_SZ + 32 + ln] = v1;
        }
    }
}

// ---------------- final: r2 reduce + 35-partial sum + f64 score + softmax ---
__global__ __launch_bounds__(256) void final_kernel(
        const float* __restrict__ z, const float* __restrict__ ws,
        const float* __restrict__ dot, float* __restrict__ out) {
    const int w = threadIdx.x >> 6, c = threadIdx.x & 63;
    const int b = blockIdx.x*4 + w;

    const floatx4 zv = *(const floatx4*)(z + b*D_SZ + c*4);
    float r2 = zv[0]*zv[0] + zv[1]*zv[1] + zv[2]*zv[2] + zv[3]*zv[3];
    #pragma unroll
    for (int off = 32; off > 0; off >>= 1)
        r2 += __shfl_xor(r2, off, 64);

    const float* __restrict__ part = ws + WS_PART;
    float Q = ws[WS_BEFF + c];
    #pragma unroll
    for (int p = 0; p < 35; ++p)
        Q += part[(size_t)p * (B_SZ*NC_SZ) + b*NC_SZ + c];

    const float csq = ws[WS_CSQ + c];
    const float dsq = fmaf(-2.f, dot[b*64 + c], r2) + csq;

    const double r2d = (double)r2, csqd = (double)csq, dsqd = (double)dsq;
    const double denom = (1.0 - r2d) * (1.0 - csqd);
    double arg = 1.0 + 2.0 * dsqd / (denom + 0.001);
    if (arg < 1.001) arg = 1.001;
    const double dist = acosh(arg);
    double tmp = 1.0 - r2d; if (tmp < 0.001) tmp = 0.001;
    double tau = 8.0 * tmp;  // sqrt(256)*0.5
    if (tau < 0.01) tau = 0.01;
    double r2c = r2d; if (r2c > 0.999) r2c = 0.999;
    const double lam = 2.0 / (1.0 - r2c + 0.001);
    const double score = -dist / tau + 0.1 * ((double)Q / lam) / tau;

    double m = score;
    #pragma unroll
    for (int off = 32; off > 0; off >>= 1) {
        double o = __shfl_xor(m, off, 64);
        m = fmax(m, o);
    }
    const double e = exp(score - m);
    double s = e;
    #pragma unroll
    for (int off = 32; off > 0; off >>= 1) s += __shfl_xor(s, off, 64);
    out[b*NC_SZ + c] = (float)(e / s);

    double bsc = score; int bix = c;
    #pragma unroll
    for (int off = 32; off > 0; off >>= 1) {
        double osc = __shfl_xor(bsc, off, 64);
        int    oix = __shfl_xor(bix, off, 64);
        if (osc > bsc || (osc == bsc && oix < bix)) { bsc = osc; bix = oix; }
    }
    if (c == 0) out[B_SZ*NC_SZ + b] = (float)bix;
}

extern "C" void kernel_launch(void* const* d_in, const int* in_sizes, int n_in,
                              void* d_out, int out_size, void* d_ws, size_t ws_size,
                              hipStream_t stream) {
    const float* z    = (const float*)d_in[0];
    const float* feat = (const float*)d_in[1];
    const float* Wqz  = (const float*)d_in[2];
    const float* bqz  = (const float*)d_in[3];
    const float* Wqf  = (const float*)d_in[4];
    const float* bqf  = (const float*)d_in[5];
    const float* gamma= (const float*)d_in[6];
    const float* cq   = (const float*)d_in[7];
    float* out = (float*)d_out;
    float* ws  = (float*)d_ws;
    _Float16* mh = (_Float16*)(ws + WS_MH);

    mid_kernel<<<1217, 256, 0, stream>>>(gamma, cq, Wqz, bqz, Wqf, bqf, ws, mh);
    qflin_kernel<<<576, 256, 0, stream>>>(z, feat, mh, ws + WS_WALL,
                                          ws + WS_PART, ws + WS_DOT);
    final_kernel<<<512, 256, 0, stream>>>(z, ws, ws + WS_DOT, out);
}

// Round 7
// 183.802 us; speedup vs baseline: 1.0705x; 1.0705x over previous
//
#include <hip/hip_runtime.h>
#include <hip/hip_bf16.h>
#include <hip/hip_fp16.h>

// B=2048, D=256, K=256, NC=64, F=512.
// Q[b,c] = Qlin[b,c] + z^T M_c z, M_c = sum_k cq[c,k] Gamma_k.
// R14: revert R13's counted-vmcnt ring (m196 failure mode: coarse-phase
// counted vmcnt = -7..-27%; measured +30us here). qf back to R12's
// per-step __syncthreads 2-buffer structure, reshaped to 128-thr blocks
// (btile 64): grid 1152 -> ~4.5 blk/CU (was 2.25 with 33% imbalance).
// mid keeps NT gamma loads. FP order per output identical to R12.

#define B_SZ 2048
#define D_SZ 256
#define K_SZ 256
#define NC_SZ 64
#define F_SZ 512
#define P_SZ 65536

typedef float  floatx4  __attribute__((ext_vector_type(4)));
typedef float  floatx16 __attribute__((ext_vector_type(16)));
typedef _Float16 h8 __attribute__((ext_vector_type(8)));
typedef __fp16  fp16x2 __attribute__((ext_vector_type(2)));
union H8U4 { uint4 u; h8 h; };

// ws layout (f32 offsets).
#define WS_BEFF  49152    // 64
#define WS_CSQ   49216    // 64
#define WS_MH    196736   // f16[64*65536] M-image (written mc, read qf)
#define WS_WALL  2293888  // 7 x 32KB pre-swizzled f16 images = 224 KB
#define WS_PART  2351232  // 35 x 131072 f32 partials (qf ig 0..31, lin2 s 0..2)
#define WS_DOT   6938752  // 131072 f32: z·cq  (slab 35)
// end: 7069824 f32 = 28.3 MB

__device__ __forceinline__ unsigned pkrtz_u(float a, float b) {
    fp16x2 r = __builtin_amdgcn_cvt_pkrtz(a, b);
    return __builtin_bit_cast(unsigned, r);
}
__device__ __forceinline__ _Float16 h16rtz(float x) {
    fp16x2 r = __builtin_amdgcn_cvt_pkrtz(x, x);
    return (_Float16)r[0];
}
__device__ __forceinline__ unsigned packh2(_Float16 a, _Float16 b) {
    union { _Float16 h[2]; unsigned u; } r; r.h[0] = a; r.h[1] = b; return r.u;
}

__device__ __forceinline__ void gload16(const void* g, void* l) {
    __builtin_amdgcn_global_load_lds(
        (const __attribute__((address_space(1))) unsigned*)g,
        (__attribute__((address_space(3))) unsigned*)l, 16, 0, 0);
}

// ---------------- mid: mc(bid<1024) U prep(bid>=1024) ----------------------
__global__ __launch_bounds__(256, 4) void mid_kernel(
        const float* __restrict__ gamma, const float* __restrict__ cq,
        const float* __restrict__ Wqz,  const float* __restrict__ bqz,
        const float* __restrict__ Wqf,  const float* __restrict__ bqf,
        float* __restrict__ ws, _Float16* __restrict__ mh) {
    __shared__ float cqL[64*129];   // 33 KB (prep path only)
    const int tid = threadIdx.x;
    const int bid = blockIdx.x;

    if (bid < 1024) {   // ---- mc ----
        const int w = tid >> 6, lane = tid & 63;
        const int ln = lane & 31, half = lane >> 5;
        const int mt = w >> 1, ns = w & 1;
        const int p0 = bid * 64;
        const int iseg = p0 >> 8, j0 = p0 & 255;
        const int rot = bid & 15;

        floatx16 acc;
        #pragma unroll
        for (int r = 0; r < 16; ++r) acc[r] = 0.f;

        const int arow = mt*32 + ln;
        const float* __restrict__ cqrow = cq + arow*256;
        const float* __restrict__ gbase =
            gamma + (size_t)(half*8)*P_SZ + p0 + ns*32 + ln;

        #pragma unroll 2
        for (int t = 0; t < 16; ++t) {
            const int kc = (t + rot) & 15;
            float g[8];
            #pragma unroll
            for (int kk = 0; kk < 8; ++kk)
                g[kk] = __builtin_nontemporal_load(
                    gbase + (size_t)(kc*16 + kk)*P_SZ);   // read-once stream
            const floatx4* cp = (const floatx4*)(cqrow + kc*16 + half*8);
            floatx4 ca = cp[0], cb = cp[1];
            H8U4 a;
            a.u.x = pkrtz_u(ca[0], ca[1]); a.u.y = pkrtz_u(ca[2], ca[3]);
            a.u.z = pkrtz_u(cb[0], cb[1]); a.u.w = pkrtz_u(cb[2], cb[3]);
            H8U4 b;
            b.u.x = pkrtz_u(g[0], g[1]);
            b.u.y = pkrtz_u(g[2], g[3]);
            b.u.z = pkrtz_u(g[4], g[5]);
            b.u.w = pkrtz_u(g[6], g[7]);
            acc = __builtin_amdgcn_mfma_f32_32x32x16_f16(a.h, b.h, acc, 0, 0, 0);
        }
        // D: col=lane&31 (p), row=(r&3)+8*(r>>2)+4*half (c)  [m74/m101]
        #pragma unroll
        for (int r = 0; r < 16; ++r) {
            const int cc = mt*32 + (r&3) + 8*(r>>2) + 4*half;
            const int j  = j0 + ns*32 + ln;
            const int jc = j >> 3, off = j & 7;
            mh[(size_t)cc*P_SZ + iseg*256 + ((jc ^ (cc&31))*8 + off)] =
                (_Float16)acc[r];
        }
        return;
    }

    // ---- prep ----
    const int pbid = bid - 1024;      // 0..192
    const int w = tid >> 6, c = tid & 63;
    char* wall = (char*)(ws + WS_WALL);

    float a0 = 0.f, a1 = 0.f, a2 = 0.f, a3 = 0.f;
    float bacc = 0.f, cacc = 0.f, cqv = 0.f;
    const int i_or_j = (pbid < 64) ? pbid*4 + w :
                       (pbid < 192) ? (pbid - 64)*4 + w : 0;

    for (int h = 0; h < 2; ++h) {
        #pragma unroll
        for (int s8 = 0; s8 < 8; ++s8) {
            const int e4 = s8*256 + tid;
            const int row = e4 >> 5, col4 = (e4 & 31)*4;
            floatx4 v = *(const floatx4*)(cq + row*256 + h*128 + col4);
            #pragma unroll
            for (int u = 0; u < 4; ++u) cqL[row*129 + col4 + u] = v[u];
        }
        __syncthreads();

        if (pbid < 64) {
            const int i = i_or_j;
            #pragma unroll 8
            for (int kk = 0; kk < 128; kk += 4) {
                const int k = h*128 + kk;
                a0 = fmaf(cqL[c*129 + kk    ], Wqz[(k    )*D_SZ + i], a0);
                a1 = fmaf(cqL[c*129 + kk + 1], Wqz[(k + 1)*D_SZ + i], a1);
                a2 = fmaf(cqL[c*129 + kk + 2], Wqz[(k + 2)*D_SZ + i], a2);
                a3 = fmaf(cqL[c*129 + kk + 3], Wqz[(k + 3)*D_SZ + i], a3);
            }
            if ((i >> 7) == h) cqv = cqL[c*129 + (i & 127)];
        } else if (pbid < 192) {
            const int j = i_or_j;
            #pragma unroll 8
            for (int kk = 0; kk < 128; kk += 4) {
                const int k = h*128 + kk;
                a0 = fmaf(cqL[c*129 + kk    ], Wqf[(k    )*F_SZ + j], a0);
                a1 = fmaf(cqL[c*129 + kk + 1], Wqf[(k + 1)*F_SZ + j], a1);
                a2 = fmaf(cqL[c*129 + kk + 2], Wqf[(k + 2)*F_SZ + j], a2);
                a3 = fmaf(cqL[c*129 + kk + 3], Wqf[(k + 3)*F_SZ + j], a3);
            }
        } else {
            if (w == 0) {
                for (int kk = 0; kk < 128; ++kk) {
                    const int k = h*128 + kk;
                    bacc = fmaf(cqL[c*129 + kk], bqz[k] + bqf[k], bacc);
                }
            } else if (w == 1) {
                for (int ii = 0; ii < 128; ++ii) {
                    const float v = cqL[c*129 + ii];
                    cacc = fmaf(v, v, cacc);
                }
            }
        }
        __syncthreads();
    }

    if (pbid < 64) {
        const int i = i_or_j;
        const int boff = c*512 + ((((i >> 3) & 31) ^ (c & 31)) << 4) + (i & 7)*2;
        *(_Float16*)(wall + 0*32768 + boff) = (_Float16)((a0 + a1) + (a2 + a3));
        const _Float16 vh = (_Float16)cqv;
        *(_Float16*)(wall + 5*32768 + boff) = vh;
        *(_Float16*)(wall + 6*32768 + boff) = h16rtz((cqv - (float)vh) * 1024.f);
    } else if (pbid < 192) {
        const int j = i_or_j;
        const float acc = (a0 + a1) + (a2 + a3);
        const int row = j & 255;
        const int sbase = (j < 256) ? 1 : 3;
        const int boff = c*512 + ((((row >> 3) & 31) ^ (c & 31)) << 4) + (row & 7)*2;
        const _Float16 ah = (_Float16)acc;
        *(_Float16*)(wall + (size_t)sbase*32768 + boff) = ah;
        *(_Float16*)(wall + (size_t)(sbase + 1)*32768 + boff) =
            h16rtz((acc - (float)ah) * 1024.f);
    } else {
        if (w == 0) ws[WS_BEFF + c] = bacc;
        else if (w == 1) ws[WS_CSQ + c] = cacc;
    }
}

// ---------------- qflin: lin2(bid<128) U qf(bid>=128), 128-thr blocks ------
// qf: btile=64 (2 waves), 2x16KB double buffer, per-step __syncthreads with
// stage-after-barrier (drained stage is one compute phase old). grid 1024 qf
// + 128 lin2 = 1152 blocks -> ~4.5 blk/CU (LDS cap 5): load-balanced TLP.
__global__ __launch_bounds__(128) void qflin_kernel(
        const float* __restrict__ z, const float* __restrict__ feat,
        const _Float16* __restrict__ mh, const float* __restrict__ wall_f,
        float* __restrict__ part, float* __restrict__ dot) {
    __shared__ __align__(16) char bt[2][16384];
    const int tid = threadIdx.x;
    const int w = tid >> 6, lane = tid & 63;
    const int ln = lane & 31, half = lane >> 5;

    if (blockIdx.x >= 128) {   // ---- qf ----
        const int bid = blockIdx.x - 128;
        const int xcd = bid & 7;
        const int y   = bid >> 3;          // 0..127
        const int ig  = xcd*4 + (y & 3);   // 0..31, same ig -> same xcd
        const int b0  = (y >> 2) * 64;     // 32 b-tiles
        const int bb  = b0 + w*32 + ln;

        #define STAGE_Q(ii, hs, sel)                                          \
            _Pragma("unroll")                                                 \
            for (int e0 = 0; e0 < 8; ++e0) {                                  \
                const int e = e0*128 + tid;                                   \
                const int cc = e >> 4, up = e & 15;                           \
                const int u = (((hs) ^ ((cc >> 4) & 1)) << 4) | up;           \
                gload16((const char*)mh +                                     \
                        ((size_t)cc*P_SZ + (size_t)(ii)*256)*2 + u*16,        \
                        bt[sel] + e*16);                                      \
            }

        STAGE_Q(ig*8, 0, 0);   // DMA overlaps the z prologue

        uint4 zjh[16];
        #pragma unroll
        for (int ch = 0; ch < 16; ++ch) {
            const floatx4* zp = (const floatx4*)(z + bb*D_SZ + ch*16 + half*8);
            floatx4 a = zp[0], b = zp[1];
            zjh[ch].x = pkrtz_u(a[0], a[1]);
            zjh[ch].y = pkrtz_u(a[2], a[3]);
            zjh[ch].z = pkrtz_u(b[0], b[1]);
            zjh[ch].w = pkrtz_u(b[2], b[3]);
        }
        float ziv[8];
        {
            const floatx4* zp = (const floatx4*)(z + bb*D_SZ + ig*8);
            floatx4 a = zp[0], b = zp[1];
            #pragma unroll
            for (int t = 0; t < 4; ++t) { ziv[t] = a[t]; ziv[4+t] = b[t]; }
        }

        floatx16 acc0, acc1;
        #pragma unroll
        for (int r = 0; r < 16; ++r) { acc0[r] = 0.f; acc1[r] = 0.f; }

        for (int t = 0; t < 16; ++t) {
            __syncthreads();   // drains stage(t) (one compute phase old)
            if (t < 15) {
                const int tn = t + 1;
                STAGE_Q(ig*8 + (tn >> 1), tn & 1, tn & 1);
            }
            const int il = t >> 1, hs = t & 1;
            const float zi = ziv[il];
            const unsigned zu = pkrtz_u(zi, zi);
            H8U4 zb; zb.u.x = zu; zb.u.y = zu; zb.u.z = zu; zb.u.w = zu;
            const char* btc = bt[t & 1];
            __builtin_amdgcn_s_setprio(1);
            #pragma unroll
            for (int chp = 0; chp < 8; ++chp) {
                H8U4 aj; aj.u = zjh[hs*8 + chp];
                h8 af = aj.h * zb.h;
                const int po = (((chp*2 + half) ^ (ln & 15)) << 4);
                H8U4 f0, f1;
                f0.u = *(const uint4*)(btc + ln*256 + po);
                f1.u = *(const uint4*)(btc + 8192 + ln*256 + po);
                acc0 = __builtin_amdgcn_mfma_f32_32x32x16_f16(af, f0.h, acc0, 0, 0, 0);
                acc1 = __builtin_amdgcn_mfma_f32_32x32x16_f16(af, f1.h, acc1, 0, 0, 0);
            }
            __builtin_amdgcn_s_setprio(0);
        }
        #undef STAGE_Q

        float* __restrict__ qp = part + (size_t)ig * (B_SZ * NC_SZ);
        #pragma unroll
        for (int r = 0; r < 16; ++r) {
            const int row  = (r&3) + 8*(r>>2) + 4*half;
            const int brow = b0 + w*32 + row;
            qp[brow*NC_SZ + ln]      = acc0[r];
            qp[brow*NC_SZ + 32 + ln] = acc1[r];
        }
        return;
    }

    // ---- lin2 ----
    const char* wall = (const char*)wall_f;
    const int lbid = blockIdx.x;          // 0..127
    const int b0 = (lbid >> 2) * 64;      // 32 b-tiles
    const int s  = lbid & 3;
    const int bb = b0 + w*32 + ln;
    const int s_hi = (s == 0) ? 0 : (s == 1) ? 1 : (s == 2) ? 3 : 5;
    const float* __restrict__ arow =
        (s == 0 || s == 3) ? z + bb*D_SZ : feat + bb*F_SZ + (s == 2 ? 256 : 0);

    #define STAGE_L(img, h, sel)                                              \
        _Pragma("unroll")                                                     \
        for (int e0 = 0; e0 < 8; ++e0) {                                      \
            const int e = e0*128 + tid;                                       \
            const int cc = e >> 4, up = e & 15;                               \
            const int u = (((h) ^ ((cc >> 4) & 1)) << 4) | up;                \
            gload16(wall + (size_t)(img)*32768 + cc*512 + u*16,               \
                    bt[sel] + e*16);                                          \
        }

    floatx16 hh0, hh1, lh0, lh1, hl0, hl1;
    #pragma unroll
    for (int r = 0; r < 16; ++r) {
        hh0[r] = 0.f; hh1[r] = 0.f; lh0[r] = 0.f;
        lh1[r] = 0.f; hl0[r] = 0.f; hl1[r] = 0.f;
    }

    for (int h = 0; h < 2; ++h) {
        STAGE_L(s_hi, h, 0);
        if (s > 0) { STAGE_L(s_hi + 1, h, 1); }
        __syncthreads();

        #pragma unroll
        for (int chp = 0; chp < 8; ++chp) {
            const int kb = h*128 + chp*16 + half*8;
            const floatx4* ap = (const floatx4*)(arow + kb);
            floatx4 a4 = ap[0], b4 = ap[1];
            float vv[8];
            #pragma unroll
            for (int t = 0; t < 4; ++t) { vv[t] = a4[t]; vv[4+t] = b4[t]; }
            _Float16 hc[8];
            #pragma unroll
            for (int j = 0; j < 8; ++j) hc[j] = (_Float16)vv[j];
            H8U4 ah;
            ah.u.x = packh2(hc[0], hc[1]); ah.u.y = packh2(hc[2], hc[3]);
            ah.u.z = packh2(hc[4], hc[5]); ah.u.w = packh2(hc[6], hc[7]);

            const int po = (((chp*2 + half) ^ (ln & 15)) << 4);
            H8U4 f0, f1;
            f0.u = *(const uint4*)(bt[0] + ln*256 + po);
            f1.u = *(const uint4*)(bt[0] + 8192 + ln*256 + po);
            hh0 = __builtin_amdgcn_mfma_f32_32x32x16_f16(ah.h, f0.h, hh0, 0, 0, 0);
            hh1 = __builtin_amdgcn_mfma_f32_32x32x16_f16(ah.h, f1.h, hh1, 0, 0, 0);

            if (s > 0) {
                float l[8];
                #pragma unroll
                for (int j = 0; j < 8; ++j) l[j] = (vv[j] - (float)hc[j]) * 1024.f;
                H8U4 al;
                al.u.x = pkrtz_u(l[0], l[1]); al.u.y = pkrtz_u(l[2], l[3]);
                al.u.z = pkrtz_u(l[4], l[5]); al.u.w = pkrtz_u(l[6], l[7]);
                H8U4 g0, g1;
                g0.u = *(const uint4*)(bt[1] + ln*256 + po);
                g1.u = *(const uint4*)(bt[1] + 8192 + ln*256 + po);
                lh0 = __builtin_amdgcn_mfma_f32_32x32x16_f16(al.h, f0.h, lh0, 0, 0, 0);
                lh1 = __builtin_amdgcn_mfma_f32_32x32x16_f16(al.h, f1.h, lh1, 0, 0, 0);
                hl0 = __builtin_amdgcn_mfma_f32_32x32x16_f16(ah.h, g0.h, hl0, 0, 0, 0);
                hl1 = __builtin_amdgcn_mfma_f32_32x32x16_f16(ah.h, g1.h, hl1, 0, 0, 0);
            }
        }
        if (h == 0) __syncthreads();   // protect bt before restage
    }
    #undef STAGE_L

    const float is = 1.0f / 1024.0f;
    float* __restrict__ qp = part + (size_t)(32 + s) * (B_SZ * NC_SZ);
    #pragma unroll
    for (int r = 0; r < 16; ++r) {
        const int row  = (r&3) + 8*(r>>2) + 4*half;
        const int brow = b0 + w*32 + row;
        float v0 = hh0[r], v1 = hh1[r];
        if (s > 0) { v0 += (lh0[r] + hl0[r])*is; v1 += (lh1[r] + hl1[r])*is; }
        if (s < 3) {
            qp[brow*NC_SZ + ln]      = v0;
            qp[brow*NC_SZ + 32 + ln] = v1;
        } else {
            dot[brow*NC_SZ + ln]      = v0;
            dot[brow*NC_SZ + 32 + ln] = v1;
        }
    }
}

// ---------------- final: r2 reduce + 35-partial sum + f64 score + softmax ---
__global__ __launch_bounds__(256) void final_kernel(
        const float* __restrict__ z, const float* __restrict__ ws,
        const float* __restrict__ dot, float* __restrict__ out) {
    const int w = threadIdx.x >> 6, c = threadIdx.x & 63;
    const int b = blockIdx.x*4 + w;

    const floatx4 zv = *(const floatx4*)(z + b*D_SZ + c*4);
    float r2 = zv[0]*zv[0] + zv[1]*zv[1] + zv[2]*zv[2] + zv[3]*zv[3];
    #pragma unroll
    for (int off = 32; off > 0; off >>= 1)
        r2 += __shfl_xor(r2, off, 64);

    const float* __restrict__ part = ws + WS_PART;
    float Q = ws[WS_BEFF + c];
    #pragma unroll
    for (int p = 0; p < 35; ++p)
        Q += part[(size_t)p * (B_SZ*NC_SZ) + b*NC_SZ + c];

    const float csq = ws[WS_CSQ + c];
    const float dsq = fmaf(-2.f, dot[b*64 + c], r2) + csq;

    const double r2d = (double)r2, csqd = (double)csq, dsqd = (double)dsq;
    const double denom = (1.0 - r2d) * (1.0 - csqd);
    double arg = 1.0 + 2.0 * dsqd / (denom + 0.001);
    if (arg < 1.001) arg = 1.001;
    const double dist = acosh(arg);
    double tmp = 1.0 - r2d; if (tmp < 0.001) tmp = 0.001;
    double tau = 8.0 * tmp;  // sqrt(256)*0.5
    if (tau < 0.01) tau = 0.01;
    double r2c = r2d; if (r2c > 0.999) r2c = 0.999;
    const double lam = 2.0 / (1.0 - r2c + 0.001);
    const double score = -dist / tau + 0.1 * ((double)Q / lam) / tau;

    double m = score;
    #pragma unroll
    for (int off = 32; off > 0; off >>= 1) {
        double o = __shfl_xor(m, off, 64);
        m = fmax(m, o);
    }
    const double e = exp(score - m);
    double s = e;
    #pragma unroll
    for (int off = 32; off > 0; off >>= 1) s += __shfl_xor(s, off, 64);
    out[b*NC_SZ + c] = (float)(e / s);

    double bsc = score; int bix = c;
    #pragma unroll
    for (int off = 32; off > 0; off >>= 1) {
        double osc = __shfl_xor(bsc, off, 64);
        int    oix = __shfl_xor(bix, off, 64);
        if (osc > bsc || (osc == bsc && oix < bix)) { bsc = osc; bix = oix; }
    }
    if (c == 0) out[B_SZ*NC_SZ + b] = (float)bix;
}

extern "C" void kernel_launch(void* const* d_in, const int* in_sizes, int n_in,
                              void* d_out, int out_size, void* d_ws, size_t ws_size,
                              hipStream_t stream) {
    const float* z    = (const float*)d_in[0];
    const float* feat = (const float*)d_in[1];
    const float* Wqz  = (const float*)d_in[2];
    const float* bqz  = (const float*)d_in[3];
    const float* Wqf  = (const float*)d_in[4];
    const float* bqf  = (const float*)d_in[5];
    const float* gamma= (const float*)d_in[6];
    const float* cq   = (const float*)d_in[7];
    float* out = (float*)d_out;
    float* ws  = (float*)d_ws;
    _Float16* mh = (_Float16*)(ws + WS_MH);

    mid_kernel<<<1217, 256, 0, stream>>>(gamma, cq, Wqz, bqz, Wqf, bqf, ws, mh);
    qflin_kernel<<<1152, 128, 0, stream>>>(z, feat, mh, ws + WS_WALL,
                                           ws + WS_PART, ws + WS_DOT);
    final_kernel<<<512, 256, 0, stream>>>(z, ws, ws + WS_DOT, out);
}

// Round 8
// 152.177 us; speedup vs baseline: 1.2930x; 1.2078x over previous
//
#include <hip/hip_runtime.h>
#include <hip/hip_bf16.h>
#include <hip/hip_fp16.h>

// B=2048, D=256, K=256, NC=64, F=512.
// Q[b,c] = Qlin[b,c] + z^T M_c z, M_c = sum_k cq[c,k] Gamma_k.
// R15: qflin reverted to R12-exact (R13 ring and R14 128-thr both measured
// regressions). mc rebuilt as LDS-staged streamer: p-window 128, k-chunks
// of 16 staged via global_load_lds dwordx4 (512B DRAM runs, 16x fewer load
// instrs; was 4B/lane strided reads at ~1.6TB/s, mid ~40us vs 10us floor).
// prep unchanged (33KB LDS pool shared with mc tiles).

#define B_SZ 2048
#define D_SZ 256
#define K_SZ 256
#define NC_SZ 64
#define F_SZ 512
#define P_SZ 65536

typedef float  floatx4  __attribute__((ext_vector_type(4)));
typedef float  floatx16 __attribute__((ext_vector_type(16)));
typedef _Float16 h8 __attribute__((ext_vector_type(8)));
typedef __fp16  fp16x2 __attribute__((ext_vector_type(2)));
union H8U4 { uint4 u; h8 h; };

// ws layout (f32 offsets).
#define WS_BEFF  49152    // 64
#define WS_CSQ   49216    // 64
#define WS_MH    196736   // f16[64*65536] M-image (written mc, read qf)
#define WS_WALL  2293888  // 7 x 32KB pre-swizzled f16 images = 224 KB
#define WS_PART  2351232  // 35 x 131072 f32 partials (qf ig 0..31, lin2 s 0..2)
#define WS_DOT   6938752  // 131072 f32: z·cq  (slab 35)
// end: 7069824 f32 = 28.3 MB

__device__ __forceinline__ unsigned pkrtz_u(float a, float b) {
    fp16x2 r = __builtin_amdgcn_cvt_pkrtz(a, b);
    return __builtin_bit_cast(unsigned, r);
}
__device__ __forceinline__ _Float16 h16rtz(float x) {
    fp16x2 r = __builtin_amdgcn_cvt_pkrtz(x, x);
    return (_Float16)r[0];
}
__device__ __forceinline__ unsigned packh2(_Float16 a, _Float16 b) {
    union { _Float16 h[2]; unsigned u; } r; r.h[0] = a; r.h[1] = b; return r.u;
}

__device__ __forceinline__ void gload16(const void* g, void* l) {
    __builtin_amdgcn_global_load_lds(
        (const __attribute__((address_space(1))) unsigned*)g,
        (__attribute__((address_space(3))) unsigned*)l, 16, 0, 0);
}

// ---------------- mid: mc(bid<512) U prep(bid>=512) ------------------------
// mc: p-window 128 per block. k-chunks of 16 rows x 128 p = 8KB f32 tile,
// double-buffered in LDS (16KB), staged with gload16 (1KB/wave-instr,
// 512B contiguous DRAM runs). Waves: mt=w>>1 -> c-half, ns=w&1 -> p-half.
// Per chunk per wave: 16 ds_read_b32 (conflict-free) + 12 pkrtz + 2 MFMA.
__global__ __launch_bounds__(256, 4) void mid_kernel(
        const float* __restrict__ gamma, const float* __restrict__ cq,
        const float* __restrict__ Wqz,  const float* __restrict__ bqz,
        const float* __restrict__ Wqf,  const float* __restrict__ bqf,
        float* __restrict__ ws, _Float16* __restrict__ mh) {
    __shared__ __align__(16) float cqL[64*129];   // 33 KB pool (prep); mc uses 16KB
    const int tid = threadIdx.x;
    const int bid = blockIdx.x;

    if (bid < 512) {   // ---- mc ----
        const int w = tid >> 6, lane = tid & 63;
        const int ln = lane & 31, half = lane >> 5;
        const int mt = w >> 1, ns = w & 1;
        const int p0 = bid * 128;
        const int iseg = p0 >> 8, j0 = p0 & 255;
        char* bt = (char*)cqL;   // 2 x 8KB tiles

        floatx16 acc0, acc1;
        #pragma unroll
        for (int r = 0; r < 16; ++r) { acc0[r] = 0.f; acc1[r] = 0.f; }

        const float* __restrict__ cqrow = cq + (mt*32 + ln)*256;

        // stage k-chunk kc (rows kc*16..+15, cols p0..p0+127) into bt[sel]
        #define STAGE_G(kc, sel)                                              \
            _Pragma("unroll")                                                 \
            for (int e0 = 0; e0 < 2; ++e0) {                                  \
                const int e = e0*256 + tid;                                   \
                gload16(gamma + (size_t)((kc)*16 + (e >> 5))*P_SZ             \
                              + p0 + (e & 31)*4,                              \
                        bt + (sel)*8192 + e*16);                              \
            }

        STAGE_G(0, 0);
        for (int t = 0; t < 16; ++t) {
            __syncthreads();   // drains stage(t) (one compute phase old)
            if (t < 15) { STAGE_G(t + 1, (t + 1) & 1); }

            // A fragment: cq row (mt*32+ln), k = t*16 + half*8 .. +7
            const floatx4* ap = (const floatx4*)(cqrow + t*16 + half*8);
            floatx4 ca = ap[0], cb = ap[1];
            H8U4 a;
            a.u.x = pkrtz_u(ca[0], ca[1]); a.u.y = pkrtz_u(ca[2], ca[3]);
            a.u.z = pkrtz_u(cb[0], cb[1]); a.u.w = pkrtz_u(cb[2], cb[3]);

            // B fragments from LDS tile [16][128] f32
            const char* btc = bt + (t & 1)*8192;
            float g0[8], g1[8];
            #pragma unroll
            for (int kk = 0; kk < 8; ++kk) {
                const int roff = (half*8 + kk)*512;
                g0[kk] = *(const float*)(btc + roff + (ns*64 + ln)*4);
                g1[kk] = *(const float*)(btc + roff + (ns*64 + 32 + ln)*4);
            }
            H8U4 b0, b1;
            b0.u.x = pkrtz_u(g0[0], g0[1]); b0.u.y = pkrtz_u(g0[2], g0[3]);
            b0.u.z = pkrtz_u(g0[4], g0[5]); b0.u.w = pkrtz_u(g0[6], g0[7]);
            b1.u.x = pkrtz_u(g1[0], g1[1]); b1.u.y = pkrtz_u(g1[2], g1[3]);
            b1.u.z = pkrtz_u(g1[4], g1[5]); b1.u.w = pkrtz_u(g1[6], g1[7]);

            acc0 = __builtin_amdgcn_mfma_f32_32x32x16_f16(a.h, b0.h, acc0, 0, 0, 0);
            acc1 = __builtin_amdgcn_mfma_f32_32x32x16_f16(a.h, b1.h, acc1, 0, 0, 0);
        }
        #undef STAGE_G

        // D: col=lane&31 (p), row=(r&3)+8*(r>>2)+4*half (c)  [m74/m101]
        #pragma unroll
        for (int r = 0; r < 16; ++r) {
            const int cc = mt*32 + (r&3) + 8*(r>>2) + 4*half;
            const int ja = j0 + ns*64 + ln;
            const int jb = j0 + ns*64 + 32 + ln;
            const size_t base = (size_t)cc*P_SZ + iseg*256;
            mh[base + (((ja >> 3) ^ (cc&31))*8 + (ja & 7))] = (_Float16)acc0[r];
            mh[base + (((jb >> 3) ^ (cc&31))*8 + (jb & 7))] = (_Float16)acc1[r];
        }
        return;
    }

    // ---- prep ----
    const int pbid = bid - 512;      // 0..192
    const int w = tid >> 6, c = tid & 63;
    char* wall = (char*)(ws + WS_WALL);

    float a0 = 0.f, a1 = 0.f, a2 = 0.f, a3 = 0.f;
    float bacc = 0.f, cacc = 0.f, cqv = 0.f;
    const int i_or_j = (pbid < 64) ? pbid*4 + w :
                       (pbid < 192) ? (pbid - 64)*4 + w : 0;

    for (int h = 0; h < 2; ++h) {
        #pragma unroll
        for (int s8 = 0; s8 < 8; ++s8) {
            const int e4 = s8*256 + tid;
            const int row = e4 >> 5, col4 = (e4 & 31)*4;
            floatx4 v = *(const floatx4*)(cq + row*256 + h*128 + col4);
            #pragma unroll
            for (int u = 0; u < 4; ++u) cqL[row*129 + col4 + u] = v[u];
        }
        __syncthreads();

        if (pbid < 64) {
            const int i = i_or_j;
            #pragma unroll 8
            for (int kk = 0; kk < 128; kk += 4) {
                const int k = h*128 + kk;
                a0 = fmaf(cqL[c*129 + kk    ], Wqz[(k    )*D_SZ + i], a0);
                a1 = fmaf(cqL[c*129 + kk + 1], Wqz[(k + 1)*D_SZ + i], a1);
                a2 = fmaf(cqL[c*129 + kk + 2], Wqz[(k + 2)*D_SZ + i], a2);
                a3 = fmaf(cqL[c*129 + kk + 3], Wqz[(k + 3)*D_SZ + i], a3);
            }
            if ((i >> 7) == h) cqv = cqL[c*129 + (i & 127)];
        } else if (pbid < 192) {
            const int j = i_or_j;
            #pragma unroll 8
            for (int kk = 0; kk < 128; kk += 4) {
                const int k = h*128 + kk;
                a0 = fmaf(cqL[c*129 + kk    ], Wqf[(k    )*F_SZ + j], a0);
                a1 = fmaf(cqL[c*129 + kk + 1], Wqf[(k + 1)*F_SZ + j], a1);
                a2 = fmaf(cqL[c*129 + kk + 2], Wqf[(k + 2)*F_SZ + j], a2);
                a3 = fmaf(cqL[c*129 + kk + 3], Wqf[(k + 3)*F_SZ + j], a3);
            }
        } else {
            if (w == 0) {
                for (int kk = 0; kk < 128; ++kk) {
                    const int k = h*128 + kk;
                    bacc = fmaf(cqL[c*129 + kk], bqz[k] + bqf[k], bacc);
                }
            } else if (w == 1) {
                for (int ii = 0; ii < 128; ++ii) {
                    const float v = cqL[c*129 + ii];
                    cacc = fmaf(v, v, cacc);
                }
            }
        }
        __syncthreads();
    }

    if (pbid < 64) {
        const int i = i_or_j;
        const int boff = c*512 + ((((i >> 3) & 31) ^ (c & 31)) << 4) + (i & 7)*2;
        *(_Float16*)(wall + 0*32768 + boff) = (_Float16)((a0 + a1) + (a2 + a3));
        const _Float16 vh = (_Float16)cqv;
        *(_Float16*)(wall + 5*32768 + boff) = vh;
        *(_Float16*)(wall + 6*32768 + boff) = h16rtz((cqv - (float)vh) * 1024.f);
    } else if (pbid < 192) {
        const int j = i_or_j;
        const float acc = (a0 + a1) + (a2 + a3);
        const int row = j & 255;
        const int sbase = (j < 256) ? 1 : 3;
        const int boff = c*512 + ((((row >> 3) & 31) ^ (c & 31)) << 4) + (row & 7)*2;
        const _Float16 ah = (_Float16)acc;
        *(_Float16*)(wall + (size_t)sbase*32768 + boff) = ah;
        *(_Float16*)(wall + (size_t)(sbase + 1)*32768 + boff) =
            h16rtz((acc - (float)ah) * 1024.f);
    } else {
        if (w == 0) ws[WS_BEFF + c] = bacc;
        else if (w == 1) ws[WS_CSQ + c] = cacc;
    }
}

// ---------------- qflin: lin2(bid<64) U qf(bid>=64) — R12-exact -------------
__global__ __launch_bounds__(256, 3) void qflin_kernel(
        const float* __restrict__ z, const float* __restrict__ feat,
        const _Float16* __restrict__ mh, const float* __restrict__ wall_f,
        float* __restrict__ part, float* __restrict__ dot) {
    __shared__ __align__(16) char bt[2][16384];
    const int tid = threadIdx.x;
    const int w = tid >> 6, lane = tid & 63;
    const int ln = lane & 31, half = lane >> 5;

    if (blockIdx.x >= 64) {   // ---- qf ----
        const int bid = blockIdx.x - 64;
        const int xcd = bid & 7;
        const int y   = bid >> 3;          // 0..63
        const int ig  = xcd*4 + (y & 3);   // 0..31
        const int b0  = (y >> 2) * 128;
        const int bb  = b0 + w*32 + ln;

        #define STAGE_Q(ii, hs, sel)                                          \
            _Pragma("unroll")                                                 \
            for (int e0 = 0; e0 < 4; ++e0) {                                  \
                const int e = e0*256 + tid;                                   \
                const int cc = e >> 4, up = e & 15;                           \
                const int u = (((hs) ^ ((cc >> 4) & 1)) << 4) | up;           \
                gload16((const char*)mh +                                     \
                        ((size_t)cc*P_SZ + (size_t)(ii)*256)*2 + u*16,        \
                        bt[sel] + e*16);                                      \
            }

        STAGE_Q(ig*8, 0, 0);   // DMA overlaps the z prologue

        uint4 zjh[16];
        #pragma unroll
        for (int ch = 0; ch < 16; ++ch) {
            const floatx4* zp = (const floatx4*)(z + bb*D_SZ + ch*16 + half*8);
            floatx4 a = zp[0], b = zp[1];
            zjh[ch].x = pkrtz_u(a[0], a[1]);
            zjh[ch].y = pkrtz_u(a[2], a[3]);
            zjh[ch].z = pkrtz_u(b[0], b[1]);
            zjh[ch].w = pkrtz_u(b[2], b[3]);
        }
        float ziv[8];
        {
            const floatx4* zp = (const floatx4*)(z + bb*D_SZ + ig*8);
            floatx4 a = zp[0], b = zp[1];
            #pragma unroll
            for (int t = 0; t < 4; ++t) { ziv[t] = a[t]; ziv[4+t] = b[t]; }
        }

        floatx16 acc0, acc1;
        #pragma unroll
        for (int r = 0; r < 16; ++r) { acc0[r] = 0.f; acc1[r] = 0.f; }

        for (int t = 0; t < 16; ++t) {
            __syncthreads();   // drains stage(t) (one iteration old)
            if (t < 15) {
                const int tn = t + 1;
                STAGE_Q(ig*8 + (tn >> 1), tn & 1, tn & 1);
            }
            const int il = t >> 1, hs = t & 1;
            const float zi = ziv[il];
            const unsigned zu = pkrtz_u(zi, zi);
            H8U4 zb; zb.u.x = zu; zb.u.y = zu; zb.u.z = zu; zb.u.w = zu;
            const char* btc = bt[t & 1];
            __builtin_amdgcn_s_setprio(1);
            #pragma unroll
            for (int chp = 0; chp < 8; ++chp) {
                H8U4 aj; aj.u = zjh[hs*8 + chp];
                h8 af = aj.h * zb.h;
                const int po = (((chp*2 + half) ^ (ln & 15)) << 4);
                H8U4 f0, f1;
                f0.u = *(const uint4*)(btc + ln*256 + po);
                f1.u = *(const uint4*)(btc + 8192 + ln*256 + po);
                acc0 = __builtin_amdgcn_mfma_f32_32x32x16_f16(af, f0.h, acc0, 0, 0, 0);
                acc1 = __builtin_amdgcn_mfma_f32_32x32x16_f16(af, f1.h, acc1, 0, 0, 0);
            }
            __builtin_amdgcn_s_setprio(0);
        }
        #undef STAGE_Q

        float* __restrict__ qp = part + (size_t)ig * (B_SZ * NC_SZ);
        #pragma unroll
        for (int r = 0; r < 16; ++r) {
            const int row  = (r&3) + 8*(r>>2) + 4*half;
            const int brow = b0 + w*32 + row;
            qp[brow*NC_SZ + ln]      = acc0[r];
            qp[brow*NC_SZ + 32 + ln] = acc1[r];
        }
        return;
    }

    // ---- lin2 ----
    const char* wall = (const char*)wall_f;
    const int lbid = blockIdx.x;
    const int b0 = (lbid >> 2) * 128;
    const int s  = lbid & 3;
    const int bb = b0 + w*32 + ln;
    const int s_hi = (s == 0) ? 0 : (s == 1) ? 1 : (s == 2) ? 3 : 5;
    const float* __restrict__ arow =
        (s == 0 || s == 3) ? z + bb*D_SZ : feat + bb*F_SZ + (s == 2 ? 256 : 0);

    #define STAGE_L(img, h, sel)                                              \
        _Pragma("unroll")                                                     \
        for (int e0 = 0; e0 < 4; ++e0) {                                      \
            const int e = e0*256 + tid;                                       \
            const int cc = e >> 4, up = e & 15;                               \
            const int u = (((h) ^ ((cc >> 4) & 1)) << 4) | up;                \
            gload16(wall + (size_t)(img)*32768 + cc*512 + u*16,               \
                    bt[sel] + e*16);                                          \
        }

    floatx16 hh0, hh1, lh0, lh1, hl0, hl1;
    #pragma unroll
    for (int r = 0; r < 16; ++r) {
        hh0[r] = 0.f; hh1[r] = 0.f; lh0[r] = 0.f;
        lh1[r] = 0.f; hl0[r] = 0.f; hl1[r] = 0.f;
    }

    for (int h = 0; h < 2; ++h) {
        STAGE_L(s_hi, h, 0);
        if (s > 0) { STAGE_L(s_hi + 1, h, 1); }
        __syncthreads();

        #pragma unroll
        for (int chp = 0; chp < 8; ++chp) {
            const int kb = h*128 + chp*16 + half*8;
            const floatx4* ap = (const floatx4*)(arow + kb);
            floatx4 a4 = ap[0], b4 = ap[1];
            float vv[8];
            #pragma unroll
            for (int t = 0; t < 4; ++t) { vv[t] = a4[t]; vv[4+t] = b4[t]; }
            _Float16 hc[8];
            #pragma unroll
            for (int j = 0; j < 8; ++j) hc[j] = (_Float16)vv[j];
            H8U4 ah;
            ah.u.x = packh2(hc[0], hc[1]); ah.u.y = packh2(hc[2], hc[3]);
            ah.u.z = packh2(hc[4], hc[5]); ah.u.w = packh2(hc[6], hc[7]);

            const int po = (((chp*2 + half) ^ (ln & 15)) << 4);
            H8U4 f0, f1;
            f0.u = *(const uint4*)(bt[0] + ln*256 + po);
            f1.u = *(const uint4*)(bt[0] + 8192 + ln*256 + po);
            hh0 = __builtin_amdgcn_mfma_f32_32x32x16_f16(ah.h, f0.h, hh0, 0, 0, 0);
            hh1 = __builtin_amdgcn_mfma_f32_32x32x16_f16(ah.h, f1.h, hh1, 0, 0, 0);

            if (s > 0) {
                float l[8];
                #pragma unroll
                for (int j = 0; j < 8; ++j) l[j] = (vv[j] - (float)hc[j]) * 1024.f;
                H8U4 al;
                al.u.x = pkrtz_u(l[0], l[1]); al.u.y = pkrtz_u(l[2], l[3]);
                al.u.z = pkrtz_u(l[4], l[5]); al.u.w = pkrtz_u(l[6], l[7]);
                H8U4 g0, g1;
                g0.u = *(const uint4*)(bt[1] + ln*256 + po);
                g1.u = *(const uint4*)(bt[1] + 8192 + ln*256 + po);
                lh0 = __builtin_amdgcn_mfma_f32_32x32x16_f16(al.h, f0.h, lh0, 0, 0, 0);
                lh1 = __builtin_amdgcn_mfma_f32_32x32x16_f16(al.h, f1.h, lh1, 0, 0, 0);
                hl0 = __builtin_amdgcn_mfma_f32_32x32x16_f16(ah.h, g0.h, hl0, 0, 0, 0);
                hl1 = __builtin_amdgcn_mfma_f32_32x32x16_f16(ah.h, g1.h, hl1, 0, 0, 0);
            }
        }
        if (h == 0) __syncthreads();   // protect bt before restage
    }
    #undef STAGE_L

    const float is = 1.0f / 1024.0f;
    float* __restrict__ qp = part + (size_t)(32 + s) * (B_SZ * NC_SZ);
    #pragma unroll
    for (int r = 0; r < 16; ++r) {
        const int row  = (r&3) + 8*(r>>2) + 4*half;
        const int brow = b0 + w*32 + row;
        float v0 = hh0[r], v1 = hh1[r];
        if (s > 0) { v0 += (lh0[r] + hl0[r])*is; v1 += (lh1[r] + hl1[r])*is; }
        if (s < 3) {
            qp[brow*NC_SZ + ln]      = v0;
            qp[brow*NC_SZ + 32 + ln] = v1;
        } else {
            dot[brow*NC_SZ + ln]      = v0;
            dot[brow*NC_SZ + 32 + ln] = v1;
        }
    }
}

// ---------------- final: r2 reduce + 35-partial sum + f64 score + softmax ---
__global__ __launch_bounds__(256) void final_kernel(
        const float* __restrict__ z, const float* __restrict__ ws,
        const float* __restrict__ dot, float* __restrict__ out) {
    const int w = threadIdx.x >> 6, c = threadIdx.x & 63;
    const int b = blockIdx.x*4 + w;

    const floatx4 zv = *(const floatx4*)(z + b*D_SZ + c*4);
    float r2 = zv[0]*zv[0] + zv[1]*zv[1] + zv[2]*zv[2] + zv[3]*zv[3];
    #pragma unroll
    for (int off = 32; off > 0; off >>= 1)
        r2 += __shfl_xor(r2, off, 64);

    const float* __restrict__ part = ws + WS_PART;
    float Q = ws[WS_BEFF + c];
    #pragma unroll
    for (int p = 0; p < 35; ++p)
        Q += part[(size_t)p * (B_SZ*NC_SZ) + b*NC_SZ + c];

    const float csq = ws[WS_CSQ + c];
    const float dsq = fmaf(-2.f, dot[b*64 + c], r2) + csq;

    const double r2d = (double)r2, csqd = (double)csq, dsqd = (double)dsq;
    const double denom = (1.0 - r2d) * (1.0 - csqd);
    double arg = 1.0 + 2.0 * dsqd / (denom + 0.001);
    if (arg < 1.001) arg = 1.001;
    const double dist = acosh(arg);
    double tmp = 1.0 - r2d; if (tmp < 0.001) tmp = 0.001;
    double tau = 8.0 * tmp;  // sqrt(256)*0.5
    if (tau < 0.01) tau = 0.01;
    double r2c = r2d; if (r2c > 0.999) r2c = 0.999;
    const double lam = 2.0 / (1.0 - r2c + 0.001);
    const double score = -dist / tau + 0.1 * ((double)Q / lam) / tau;

    double m = score;
    #pragma unroll
    for (int off = 32; off > 0; off >>= 1) {
        double o = __shfl_xor(m, off, 64);
        m = fmax(m, o);
    }
    const double e = exp(score - m);
    double s = e;
    #pragma unroll
    for (int off = 32; off > 0; off >>= 1) s += __shfl_xor(s, off, 64);
    out[b*NC_SZ + c] = (float)(e / s);

    double bsc = score; int bix = c;
    #pragma unroll
    for (int off = 32; off > 0; off >>= 1) {
        double osc = __shfl_xor(bsc, off, 64);
        int    oix = __shfl_xor(bix, off, 64);
        if (osc > bsc || (osc == bsc && oix < bix)) { bsc = osc; bix = oix; }
    }
    if (c == 0) out[B_SZ*NC_SZ + b] = (float)bix;
}

extern "C" void kernel_launch(void* const* d_in, const int* in_sizes, int n_in,
                              void* d_out, int out_size, void* d_ws, size_t ws_size,
                              hipStream_t stream) {
    const float* z    = (const float*)d_in[0];
    const float* feat = (const float*)d_in[1];
    const float* Wqz  = (const float*)d_in[2];
    const float* bqz  = (const float*)d_in[3];
    const float* Wqf  = (const float*)d_in[4];
    const float* bqf  = (const float*)d_in[5];
    const float* gamma= (const float*)d_in[6];
    const float* cq   = (const float*)d_in[7];
    float* out = (float*)d_out;
    float* ws  = (float*)d_ws;
    _Float16* mh = (_Float16*)(ws + WS_MH);

    mid_kernel<<<705, 256, 0, stream>>>(gamma, cq, Wqz, bqz, Wqf, bqf, ws, mh);
    qflin_kernel<<<576, 256, 0, stream>>>(z, feat, mh, ws + WS_WALL,
                                          ws + WS_PART, ws + WS_DOT);
    final_kernel<<<512, 256, 0, stream>>>(z, ws, ws + WS_DOT, out);
}